// Round 4
// baseline (126.085 us; speedup 1.0000x reference)
//
#include <hip/hip_runtime.h>

// Problem constants (from reference): B=128, T=256, IN=1, H=5000, OUT=20
#define T_STEPS 256
#define BATCH   128
#define HIDDEN  5000
#define NHALF   2500   // 2 chains per thread: i and i+NHALF
#define NOUT    20
#define NBLK    10     // gridDim.x of the fused kernel

typedef float v2f __attribute__((ext_vector_type(2)));

// ---------------------------------------------------------------------------
// Fused kernel: recurrence + head partial-GEMV, transcendental-free.
//   h <- tanh(x_t*w + b + h). Track s = c*(h + b), c = 2*log2(e):
//     u   = fma(x, wc, s)            // = c*(x w + b + h) = 2*log2e*z
//     E   = 2^u  (software: rne-split + deg-7 Taylor + exponent stuff)
//     r   = 1/(1+E)  (bit-seed + 3 Newton)
//     s'  = fma(r, -2c, c + cb)      // = c*(tanh(z) + b)
//   All math on the FULL-RATE VALU via packed fp32 (v_pk_fma_f32),
//   2 chains/thread in the two halves of a v2f.
//   R3 evidence: hw exp2/rcp block issue ~16 cyc each (trans pipe), giving a
//   38 cyc/chain-step floor; this path is ~24 cyc/chain-step.
// Grid: 10 x 128 = 1280 blocks = 5 blocks/CU, one dispatch round, no tail.
// ---------------------------------------------------------------------------
__global__ __launch_bounds__(256)
void rnn_fused(const float* __restrict__ x,
               const float* __restrict__ W_in,
               const float* __restrict__ b_in,
               const float* __restrict__ W_out,
               float* __restrict__ part) {
    const int b   = blockIdx.y;
    const int tid = threadIdx.x;
    const int i0  = blockIdx.x * 256 + tid;
    const bool valid = (i0 < NHALF);
    const int j0 = valid ? i0 : 0;            // safe index for tail lanes
    const int j1 = j0 + NHALF;

    const float c     = 2.8853900817779268f;   // 2*log2(e)
    const float inv_c = 0.34657359027997264f;  // ln(2)/2

    // deg-7 Taylor of 2^t = e^{t ln2}, t in [-0.5, 0.5] (rel err ~5e-9)
    const v2f C7 = {1.5252733804059840e-05f, 1.5252733804059840e-05f};
    const v2f C6 = {1.5403530393381609e-04f, 1.5403530393381609e-04f};
    const v2f C5 = {1.3333558146428443e-03f, 1.3333558146428443e-03f};
    const v2f C4 = {9.6181291076284772e-03f, 9.6181291076284772e-03f};
    const v2f C3 = {5.5504108664821580e-02f, 5.5504108664821580e-02f};
    const v2f C2 = {2.4022650695910072e-01f, 2.4022650695910072e-01f};
    const v2f C1 = {6.9314718055994531e-01f, 6.9314718055994531e-01f};
    const v2f C0 = {1.0f, 1.0f};
    const v2f BIG = {12582912.0f, 12582912.0f};   // 1.5 * 2^23 (rne trick)
    const v2f ONE = {1.0f, 1.0f};
    const v2f TWO = {2.0f, 2.0f};
    const v2f N2C = {-5.7707801635558537f, -5.7707801635558537f}; // -2c

    const v2f wc  = { W_in[j0] * c, W_in[j1] * c };
    const v2f cb  = { b_in[j0] * c, b_in[j1] * c };
    const v2f cpb = { c + cb.x, c + cb.y };        // step constant c + c*b

    const float* __restrict__ xrow = x + b * T_STEPS;  // wave-uniform reads

    v2f s = cb;                                     // s0 = c*(h0 + b) = c*b
    #pragma unroll 8
    for (int t = 0; t < T_STEPS; ++t) {
        const float xv = xrow[t];                   // uniform -> s_load
        const v2f xv2 = {xv, xv};
        v2f u  = __builtin_elementwise_fma(xv2, wc, s);
        v2f k  = u + BIG;                           // k = BIG + rne(u), exact
        v2f fl = k - BIG;                           // fl = rne(u)
        v2f tt = u - fl;                            // tt in [-0.5, 0.5]
        // p = 2^tt
        v2f p  = __builtin_elementwise_fma(tt, C7, C6);
        p = __builtin_elementwise_fma(tt, p, C5);
        p = __builtin_elementwise_fma(tt, p, C4);
        p = __builtin_elementwise_fma(tt, p, C3);
        p = __builtin_elementwise_fma(tt, p, C2);
        p = __builtin_elementwise_fma(tt, p, C1);
        p = __builtin_elementwise_fma(tt, p, C0);
        // scale = 2^rne(u): exponent bits straight from k's low mantissa bits
        v2f sc = { __uint_as_float((__float_as_uint(k.x) << 23) + 0x3F800000u),
                   __uint_as_float((__float_as_uint(k.y) << 23) + 0x3F800000u) };
        v2f E  = p * sc;                            // e^{2z}
        v2f d  = E + ONE;
        // r = 1/d: bit-trick seed + 3 Newton (last in residual form)
        v2f y  = { __uint_as_float(0x7EF311C3u - __float_as_uint(d.x)),
                   __uint_as_float(0x7EF311C3u - __float_as_uint(d.y)) };
        v2f e  = __builtin_elementwise_fma(-d, y, TWO);
        y = y * e;
        e = __builtin_elementwise_fma(-d, y, TWO);
        y = y * e;
        e = __builtin_elementwise_fma(-d, y, ONE);
        y = __builtin_elementwise_fma(e, y, y);
        // s' = c*tanh(z) + c*b
        s = __builtin_elementwise_fma(y, N2C, cpb);
    }

    float h0 = (s.x - cb.x) * inv_c;
    float h1 = (s.y - cb.y) * inv_c;
    if (!valid) { h0 = 0.0f; h1 = 0.0f; }

    // ---- head partials: acc[o] = h0*W_out[o][j0] + h1*W_out[o][j1] ----
    float acc[NOUT];
    #pragma unroll
    for (int o = 0; o < NOUT; ++o) {
        const float w0 = W_out[o * HIDDEN + j0];    // lane-coalesced
        const float w1 = W_out[o * HIDDEN + j1];
        acc[o] = fmaf(h0, w0, h1 * w1);             // tail lanes contribute 0
    }

    // wave reduce (64 lanes)
    #pragma unroll
    for (int o = 0; o < NOUT; ++o) {
        #pragma unroll
        for (int sft = 32; sft > 0; sft >>= 1)
            acc[o] += __shfl_down(acc[o], sft, 64);
    }

    __shared__ float red[4][NOUT];
    const int wid = tid >> 6, lane = tid & 63;
    if (lane == 0) {
        #pragma unroll
        for (int o = 0; o < NOUT; ++o) red[wid][o] = acc[o];
    }
    __syncthreads();

    if (tid < NOUT) {
        const float v = red[0][tid] + red[1][tid] + red[2][tid] + red[3][tid];
        part[(b * NBLK + blockIdx.x) * NOUT + tid] = v;
    }
}

// ---------------------------------------------------------------------------
// Tiny epilogue: logits[b][o] = sum_blk part + b_out[o]; softmax over 20.
// One wave per batch row; lanes 20..63 padded (-inf for max, 0 for sum).
// ---------------------------------------------------------------------------
__global__ __launch_bounds__(64)
void softmax_head(const float* __restrict__ part,
                  const float* __restrict__ b_out,
                  float* __restrict__ out) {
    const int b = blockIdx.x;
    const int o = threadIdx.x;

    float v = -1e30f;
    if (o < NOUT) {
        float s = b_out[o];
        #pragma unroll
        for (int blk = 0; blk < NBLK; ++blk)
            s += part[(b * NBLK + blk) * NOUT + o];
        v = s;
    }

    float m = v;
    #pragma unroll
    for (int sft = 32; sft > 0; sft >>= 1) m = fmaxf(m, __shfl_xor(m, sft, 64));

    float e = (o < NOUT)
            ? __builtin_amdgcn_exp2f((v - m) * 1.4426950408889634f)
            : 0.0f;
    float ssum = e;
    #pragma unroll
    for (int sft = 32; sft > 0; sft >>= 1) ssum += __shfl_xor(ssum, sft, 64);

    if (o < NOUT) out[b * NOUT + o] = e / ssum;
}

extern "C" void kernel_launch(void* const* d_in, const int* in_sizes, int n_in,
                              void* d_out, int out_size, void* d_ws, size_t ws_size,
                              hipStream_t stream) {
    const float* x     = (const float*)d_in[0];
    const float* W_in  = (const float*)d_in[1];
    const float* b_in  = (const float*)d_in[2];
    const float* W_out = (const float*)d_in[3];
    const float* b_out = (const float*)d_in[4];
    float* out  = (float*)d_out;
    float* part = (float*)d_ws;   // [BATCH][NBLK][NOUT] f32 = 102 KB

    dim3 grid1(NBLK, BATCH);      // 10 x 128
    rnn_fused<<<grid1, 256, 0, stream>>>(x, W_in, b_in, W_out, part);
    softmax_head<<<BATCH, 64, 0, stream>>>(part, b_out, out);
}

// Round 6
// 99.747 us; speedup vs baseline: 1.2640x; 1.2640x over previous
//
#include <hip/hip_runtime.h>

// Problem constants (from reference): B=128, T=256, IN=1, H=5000, OUT=20
#define T_STEPS 256
#define BATCH   128
#define HIDDEN  5000
#define NHALF   2500   // 2 chains per thread: i and i+NHALF
#define NOUT    20
#define NBLK    10     // gridDim.x of the fused kernel
#define CH      16     // x-prefetch chunk (16 floats -> 16 SGPRs per buffer)

// ---------------------------------------------------------------------------
// Fused kernel: recurrence + head partial-GEMV.
//   h <- tanh(x_t*w + b + h). Track s = c*(h + b), c = 2*log2(e):
//     u  = fma(x, wc, s)            // = c*z, z = x*w + b + h
//     E  = exp2(u)                  // hw trans
//     d  = E + 1
//     r  = rcp(d)                   // hw trans
//     s' = fma(r, -2c, c + cb)      // = c*(tanh(z) + b)
//   3 main-VALU + 2 trans per chain-step; 2 chains/thread.
//
// R3 post-mortem: the per-step uniform x load (s_load) stalled ALL co-resident
// waves together (~29 cyc/wave-step lgkmcnt stall, lockstep). Fix here:
// ping-pong CH-float chunks (a_, b_) with the next chunk's scalar loads issued
// BEFORE the current chunk's 16 steps -> latency fully hidden under compute.
// All indices compile-time constants (no scratch).
// Grid: 10 x 128 = 1280 blocks = 5 blocks/CU uniform, 20 waves/CU.
// ---------------------------------------------------------------------------
__global__ __launch_bounds__(256)
void rnn_fused(const float* __restrict__ x,
               const float* __restrict__ W_in,
               const float* __restrict__ b_in,
               const float* __restrict__ W_out,
               float* __restrict__ part) {
    const int b   = blockIdx.y;
    const int tid = threadIdx.x;
    const int i0  = blockIdx.x * 256 + tid;
    const bool valid = (i0 < NHALF);
    const int j0 = valid ? i0 : 0;            // safe index for tail lanes
    const int j1 = j0 + NHALF;

    const float c     = 2.8853900817779268f;   // 2*log2(e)
    const float inv_c = 0.34657359027997264f;  // ln(2)/2
    const float n2c   = -5.7707801635558537f;  // -2c

    const float wc0 = W_in[j0] * c;
    const float wc1 = W_in[j1] * c;
    const float cb0 = b_in[j0] * c;
    const float cb1 = b_in[j1] * c;
    const float cpb0 = c + cb0;                // step constant c + c*b
    const float cpb1 = c + cb1;

    const float* __restrict__ xrow = x + b * T_STEPS;  // wave-uniform reads

    float s0 = cb0, s1 = cb1;                  // s = c*(h+b), h0 = 0

#define STEP1(xv)                                                   \
    {                                                               \
        const float u0 = fmaf((xv), wc0, s0);                       \
        const float u1 = fmaf((xv), wc1, s1);                       \
        const float e0 = __builtin_amdgcn_exp2f(u0);                \
        const float e1 = __builtin_amdgcn_exp2f(u1);                \
        const float r0 = __builtin_amdgcn_rcpf(e0 + 1.0f);          \
        const float r1 = __builtin_amdgcn_rcpf(e1 + 1.0f);          \
        s0 = fmaf(r0, n2c, cpb0);                                   \
        s1 = fmaf(r1, n2c, cpb1);                                   \
    }

    float a_[CH], b_[CH];
    #pragma unroll
    for (int j = 0; j < CH; ++j) a_[j] = xrow[j];          // chunk 0

    for (int base = 0; base < T_STEPS; base += 2 * CH) {   // 8 iterations
        // prefetch chunk (base+CH) while computing chunk (base)
        #pragma unroll
        for (int j = 0; j < CH; ++j) b_[j] = xrow[base + CH + j];
        #pragma unroll
        for (int j = 0; j < CH; ++j) STEP1(a_[j]);
        // prefetch chunk (base+2CH) while computing chunk (base+CH)
        if (base + 2 * CH < T_STEPS) {
            #pragma unroll
            for (int j = 0; j < CH; ++j) a_[j] = xrow[base + 2 * CH + j];
        }
        #pragma unroll
        for (int j = 0; j < CH; ++j) STEP1(b_[j]);
    }
#undef STEP1

    float h0 = (s0 - cb0) * inv_c;
    float h1 = (s1 - cb1) * inv_c;
    if (!valid) { h0 = 0.0f; h1 = 0.0f; }

    // ---- head partials: acc[o] = h0*W_out[o][j0] + h1*W_out[o][j1] ----
    float acc[NOUT];
    #pragma unroll
    for (int o = 0; o < NOUT; ++o) {
        const float w0 = W_out[o * HIDDEN + j0];    // lane-coalesced
        const float w1 = W_out[o * HIDDEN + j1];
        acc[o] = fmaf(h0, w0, h1 * w1);             // tail lanes contribute 0
    }

    // wave reduce (64 lanes)
    #pragma unroll
    for (int o = 0; o < NOUT; ++o) {
        #pragma unroll
        for (int sft = 32; sft > 0; sft >>= 1)
            acc[o] += __shfl_down(acc[o], sft, 64);
    }

    __shared__ float red[4][NOUT];
    const int wid = tid >> 6, lane = tid & 63;
    if (lane == 0) {
        #pragma unroll
        for (int o = 0; o < NOUT; ++o) red[wid][o] = acc[o];
    }
    __syncthreads();

    if (tid < NOUT) {
        const float v = red[0][tid] + red[1][tid] + red[2][tid] + red[3][tid];
        part[(b * NBLK + blockIdx.x) * NOUT + tid] = v;
    }
}

// ---------------------------------------------------------------------------
// Tiny epilogue: logits[b][o] = sum_blk part + b_out[o]; softmax over 20.
// One wave per batch row; lanes 20..63 padded (-inf for max, 0 for sum).
// ---------------------------------------------------------------------------
__global__ __launch_bounds__(64)
void softmax_head(const float* __restrict__ part,
                  const float* __restrict__ b_out,
                  float* __restrict__ out) {
    const int b = blockIdx.x;
    const int o = threadIdx.x;

    float v = -1e30f;
    if (o < NOUT) {
        float s = b_out[o];
        #pragma unroll
        for (int blk = 0; blk < NBLK; ++blk)
            s += part[(b * NBLK + blk) * NOUT + o];
        v = s;
    }

    float m = v;
    #pragma unroll
    for (int sft = 32; sft > 0; sft >>= 1) m = fmaxf(m, __shfl_xor(m, sft, 64));

    float e = (o < NOUT)
            ? __builtin_amdgcn_exp2f((v - m) * 1.4426950408889634f)
            : 0.0f;
    float ssum = e;
    #pragma unroll
    for (int sft = 32; sft > 0; sft >>= 1) ssum += __shfl_xor(ssum, sft, 64);

    if (o < NOUT) out[b * NOUT + o] = e / ssum;
}

extern "C" void kernel_launch(void* const* d_in, const int* in_sizes, int n_in,
                              void* d_out, int out_size, void* d_ws, size_t ws_size,
                              hipStream_t stream) {
    const float* x     = (const float*)d_in[0];
    const float* W_in  = (const float*)d_in[1];
    const float* b_in  = (const float*)d_in[2];
    const float* W_out = (const float*)d_in[3];
    const float* b_out = (const float*)d_in[4];
    float* out  = (float*)d_out;
    float* part = (float*)d_ws;   // [BATCH][NBLK][NOUT] f32 = 102 KB

    dim3 grid1(NBLK, BATCH);      // 10 x 128
    rnn_fused<<<grid1, 256, 0, stream>>>(x, W_in, b_in, W_out, part);
    softmax_head<<<BATCH, 64, 0, stream>>>(part, b_out, out);
}